// Round 1
// baseline (186.504 us; speedup 1.0000x reference)
//
#include <hip/hip_runtime.h>
#include <hip/hip_bf16.h>
#include <cstddef>

// SpatialConv KERNEL_TYPE=0: 5-tap plus conv, N=16 Ci=Co=256 H=W=64, fp32 I/O.
// v2 structure: 512-thread blocks, each covers ALL 256 o x 2 output rows x 64 w
//   -> no ohalf x-duplication (x HBM read 201MB -> ~131MB)
//   -> wave = 64 o x 1 row x 64 w: acc[2][2] = 64 VGPR (was 128)
//   -> target 4 waves/SIMD via __launch_bounds__(512,4) (was 2)
// LDS x-tile layout [buf][r=4][cg=4][wp=66] cells of 16B (8 bf16 channels),
// w padded to 66 with zeroed edge cells -> OOB taps read zeros, NO per-frag
// cmp/cndmask; every B read is ds_read_b128 base+imm.
#define N_  16
#define CI  256
#define CO  256
#define KT  5

typedef __attribute__((ext_vector_type(8)))  short  short8;
typedef __attribute__((ext_vector_type(8)))  unsigned short ushort8;
typedef __attribute__((ext_vector_type(4)))  unsigned int uint4v;
typedef __attribute__((ext_vector_type(16))) float  floatx16;

static __device__ __forceinline__ unsigned short f2bf(float f) {
    union { float f; unsigned u; } v; v.f = f;
    unsigned r = v.u + 0x7fff + ((v.u >> 16) & 1);   // RNE
    return (unsigned short)(r >> 16);
}

// ---- prepass: w fp32 [Co][Ci][5] -> wb bf16 [5][Co][Ci] (c contiguous) ----
__global__ void wtrans_kernel(const float* __restrict__ w, unsigned short* __restrict__ wb) {
    int idx = blockIdx.x * 256 + threadIdx.x;
    if (idx >= KT * CO * CI) return;
    int k = idx >> 16;
    int rem = idx & 65535;
    int o = rem >> 8;
    int c = rem & 255;
    wb[idx] = f2bf(w[(size_t)o * (CI * KT) + c * KT + k]);
}

// ---- main: block = 256 o x 2 rows x 64 w, 8 waves; wave = 64 o x 1 row ----
// LDS slot = buf*1056 + r*264 + cg*66 + wp ; wp = w+1, wp 0 and 65 are zero pads.
__global__ __launch_bounds__(512, 4) void conv_mfma(const float* __restrict__ x,
                                                    const unsigned short* __restrict__ wb,
                                                    float* __restrict__ out) {
    __shared__ ushort8 lds[2112];   // 2 x 16.5 KB

    const int tid = threadIdx.x;
    // XCD-aware bijective swizzle (512 blocks = 8 XCD x 64): row-neighbor
    // blocks (sharing 2 halo rows) land on the same XCD's L2.
    const int bx0 = blockIdx.x;
    const int bx  = (bx0 & 7) * 64 + (bx0 >> 3);
    const int g   = bx & 31;                    // row-pair index: rows 2g, 2g+1
    const int n   = bx >> 5;
    const int h0  = g * 2;

    const int lane  = tid & 63;
    const int wv    = tid >> 6;                 // 0..7
    const int l31   = lane & 31;
    const int lh    = lane >> 5;
    const int owave = (wv & 3) * 64;            // wave o-base (64 wide)
    const int hrow  = wv >> 2;                  // 0 or 1: which output row

    // staging role: thread owns cells (r = sr2*2+{0,1}, scg, sw)
    const int sw  = tid & 63;
    const int scg = (tid >> 6) & 3;
    const int sr2 = tid >> 8;                   // 0/1

    // zero the horizontal pad cells once (both buffers): 2buf x 4r x 4cg x 2wp = 64
    if (tid < 64) {
        int buf = tid & 1;
        int wp  = ((tid >> 1) & 1) * 65;
        int cg  = (tid >> 2) & 3;
        int r   = (tid >> 4) & 3;
        lds[buf * 1056 + r * 264 + cg * 66 + wp] = (ushort8)0;
    }

    const float* xn = x + (size_t)n * CI * 4096;

    float xr[2][8];
    auto load_chunk = [&](int c) {
        #pragma unroll
        for (int ii = 0; ii < 2; ++ii) {
            const int i  = sr2 * 2 + ii;
            const int hh = h0 - 1 + i;          // staged input row
            if ((unsigned)hh < 64u) {
                const float* p = xn + (c * 32 + scg * 8) * 4096 + hh * 64 + sw;
                #pragma unroll
                for (int e = 0; e < 8; ++e) xr[ii][e] = p[e * 4096];
            } else {
                #pragma unroll
                for (int e = 0; e < 8; ++e) xr[ii][e] = 0.f;
            }
        }
    };
    auto write_chunk = [&](int b) {
        #pragma unroll
        for (int ii = 0; ii < 2; ++ii) {
            const int i = sr2 * 2 + ii;
            uint4v v;
            #pragma unroll
            for (int e = 0; e < 4; ++e) {
                __hip_bfloat162 pk = __float22bfloat162_rn(
                    make_float2(xr[ii][2 * e], xr[ii][2 * e + 1]));
                union { __hip_bfloat162 h; unsigned u; } cv; cv.h = pk;
                v[e] = cv.u;
            }
            *(uint4v*)&lds[b * 1056 + i * 264 + scg * 66 + (sw + 1)] = v;
        }
    };

    floatx16 acc[2][2];                          // [o-tile 32][w-half]
    #pragma unroll
    for (int ot = 0; ot < 2; ++ot)
        #pragma unroll
        for (int t = 0; t < 2; ++t)
            #pragma unroll
            for (int e = 0; e < 16; ++e) acc[ot][t][e] = 0.f;

    // per-lane bases
    const char* ldsb = (const char*)lds + (hrow * 4224 + lh * 1056 + l31 * 16);
    const unsigned short* wA = wb + (owave + l31) * 256 + lh * 8;   // elements

    load_chunk(0);
    write_chunk(0);
    __syncthreads();

    for (int c = 0; c < 8; ++c) {
        if (c < 7) load_chunk(c + 1);           // regs; lands during MFMA

        const char* bufb = ldsb + (c & 1) * 16896;
        const unsigned short* wc = wA + c * 32;

        // taps (dy,dx): k0=(1,1) k1=(0,1) k2=(1,0) k3=(1,2) k4=(2,1)
        #pragma unroll
        for (int ks = 0; ks < 2; ++ks) {
            #pragma unroll
            for (int k = 0; k < KT; ++k) {
                const int dy = (k == 1) ? 0 : (k == 4) ? 2 : 1;
                const int dx = (k == 2) ? 0 : (k == 3) ? 2 : 1;
                const short8 a0 = *(const short8*)(wc + k * 65536 + ks * 16);
                const short8 a1 = *(const short8*)(wc + k * 65536 + 8192 + ks * 16);
                const short8 b0 = *(const short8*)(bufb + (dy * 264 + ks * 132 + dx) * 16);
                const short8 b1 = *(const short8*)(bufb + (dy * 264 + ks * 132 + 32 + dx) * 16);
                acc[0][0] = __builtin_amdgcn_mfma_f32_32x32x16_bf16(a0, b0, acc[0][0], 0, 0, 0);
                acc[1][0] = __builtin_amdgcn_mfma_f32_32x32x16_bf16(a1, b0, acc[1][0], 0, 0, 0);
                acc[0][1] = __builtin_amdgcn_mfma_f32_32x32x16_bf16(a0, b1, acc[0][1], 0, 0, 0);
                acc[1][1] = __builtin_amdgcn_mfma_f32_32x32x16_bf16(a1, b1, acc[1][1], 0, 0, 0);
            }
        }

        if (c < 7) write_chunk((c + 1) & 1);    // other buffer; safe after prev barrier
        __syncthreads();
    }

    // epilogue: C/D: col(px) = l31, row(o-off) = (reg&3) + 8*(reg>>2) + 4*lh
    const int h = h0 + hrow;
    #pragma unroll
    for (int ot = 0; ot < 2; ++ot) {
        #pragma unroll
        for (int wh = 0; wh < 2; ++wh) {
            #pragma unroll
            for (int reg = 0; reg < 16; ++reg) {
                int o = owave + ot * 32 + (reg & 3) + 8 * (reg >> 2) + 4 * lh;
                out[(((size_t)n * CO + o) * 64 + h) * 64 + wh * 32 + l31] = acc[ot][wh][reg];
            }
        }
    }
}

extern "C" void kernel_launch(void* const* d_in, const int* in_sizes, int n_in,
                              void* d_out, int out_size, void* d_ws, size_t ws_size,
                              hipStream_t stream) {
    const float* x = (const float*)d_in[0];
    const float* w = (const float*)d_in[1];
    float* out = (float*)d_out;

    unsigned short* wb = (unsigned short*)d_ws;    // 640 KB, the only workspace

    wtrans_kernel<<<dim3((KT * CO * CI + 255) / 256), dim3(256), 0, stream>>>(w, wb);
    conv_mfma<<<dim3(N_ * 32), dim3(512), 0, stream>>>(x, wb, out);
}

// Round 2
// 151.521 us; speedup vs baseline: 1.2309x; 1.2309x over previous
//
#include <hip/hip_runtime.h>
#include <hip/hip_bf16.h>
#include <cstddef>

// SpatialConv KERNEL_TYPE=0: 5-tap plus conv, N=16 Ci=Co=256 H=W=64, fp32 I/O.
// v3: weight layout transposed for COALESCED a-frag loads.
//   v2's a-loads were 16B/lane at 512B stride = 64 cache lines per instr
//   (25% line efficiency) -> ~2.6 GB of L2-line traffic = the hidden
//   bottleneck (all pipes <20% busy). New wb layout [k][c][ks][lh][o][8ci]
//   makes each a-frag load 2x512B contiguous (100% efficiency).
//   Also: x-prefetch issued MID-chunk (after ks=0) so the vmcnt FIFO does
//   not gate the first half of MFMAs on HBM x-loads.
#define N_  16
#define CI  256
#define CO  256
#define KT  5

typedef __attribute__((ext_vector_type(8)))  short  short8;
typedef __attribute__((ext_vector_type(8)))  unsigned short ushort8;
typedef __attribute__((ext_vector_type(4)))  unsigned int uint4v;
typedef __attribute__((ext_vector_type(16))) float  floatx16;

static __device__ __forceinline__ unsigned short f2bf(float f) {
    union { float f; unsigned u; } v; v.f = f;
    unsigned r = v.u + 0x7fff + ((v.u >> 16) & 1);   // RNE
    return (unsigned short)(r >> 16);
}

// ---- prepass: w fp32 [Co][Ci][5] -> wb bf16, layout (elements):
//   idx = ((((k*8 + c)*2 + ks)*2 + lh)*256 + o)*8 + e,  ci = c*32+ks*16+lh*8+e
// strides: e 1, o 8, lh 2048, ks 4096, c 8192, k 65536.
__global__ void wtrans_kernel(const float* __restrict__ w, unsigned short* __restrict__ wb) {
    int idx = blockIdx.x * 256 + threadIdx.x;
    if (idx >= KT * CO * CI) return;
    int e  = idx & 7;
    int o  = (idx >> 3) & 255;
    int lh = (idx >> 11) & 1;
    int ks = (idx >> 12) & 1;
    int c  = (idx >> 13) & 7;
    int k  = idx >> 16;
    int ci = c * 32 + ks * 16 + lh * 8 + e;
    wb[idx] = f2bf(w[(size_t)o * (CI * KT) + ci * KT + k]);
}

// ---- main: block = 256 o x 2 rows x 64 w, 8 waves; wave = 64 o x 1 row ----
// LDS slot = buf*1056 + r*264 + cg*66 + wp ; wp = w+1, wp 0 and 65 are zero pads.
__global__ __launch_bounds__(512, 4) void conv_mfma(const float* __restrict__ x,
                                                    const unsigned short* __restrict__ wb,
                                                    float* __restrict__ out) {
    __shared__ ushort8 lds[2112];   // 2 x 16.5 KB

    const int tid = threadIdx.x;
    // XCD-aware bijective swizzle (512 blocks = 8 XCD x 64): row-neighbor
    // blocks (sharing 2 halo rows) land on the same XCD's L2.
    const int bx0 = blockIdx.x;
    const int bx  = (bx0 & 7) * 64 + (bx0 >> 3);
    const int g   = bx & 31;                    // row-pair index: rows 2g, 2g+1
    const int n   = bx >> 5;
    const int h0  = g * 2;

    const int lane  = tid & 63;
    const int wv    = tid >> 6;                 // 0..7
    const int l31   = lane & 31;
    const int lh    = lane >> 5;
    const int owave = (wv & 3) * 64;            // wave o-base (64 wide)
    const int hrow  = wv >> 2;                  // 0 or 1: which output row

    // staging role: thread owns cells (r = sr2*2+{0,1}, scg, sw)
    const int sw  = tid & 63;
    const int scg = (tid >> 6) & 3;
    const int sr2 = tid >> 8;                   // 0/1

    // zero the horizontal pad cells once (both buffers): 2buf x 4r x 4cg x 2wp = 64
    if (tid < 64) {
        int buf = tid & 1;
        int wp  = ((tid >> 1) & 1) * 65;
        int cg  = (tid >> 2) & 3;
        int r   = (tid >> 4) & 3;
        lds[buf * 1056 + r * 264 + cg * 66 + wp] = (ushort8)0;
    }

    const float* xn = x + (size_t)n * CI * 4096;

    float xr[2][8];
    auto load_chunk = [&](int c) {
        #pragma unroll
        for (int ii = 0; ii < 2; ++ii) {
            const int i  = sr2 * 2 + ii;
            const int hh = h0 - 1 + i;          // staged input row
            if ((unsigned)hh < 64u) {
                const float* p = xn + (c * 32 + scg * 8) * 4096 + hh * 64 + sw;
                #pragma unroll
                for (int e = 0; e < 8; ++e) xr[ii][e] = p[e * 4096];
            } else {
                #pragma unroll
                for (int e = 0; e < 8; ++e) xr[ii][e] = 0.f;
            }
        }
    };
    auto write_chunk = [&](int b) {
        #pragma unroll
        for (int ii = 0; ii < 2; ++ii) {
            const int i = sr2 * 2 + ii;
            uint4v v;
            #pragma unroll
            for (int e = 0; e < 4; ++e) {
                __hip_bfloat162 pk = __float22bfloat162_rn(
                    make_float2(xr[ii][2 * e], xr[ii][2 * e + 1]));
                union { __hip_bfloat162 h; unsigned u; } cv; cv.h = pk;
                v[e] = cv.u;
            }
            *(uint4v*)&lds[b * 1056 + i * 264 + scg * 66 + (sw + 1)] = v;
        }
    };

    floatx16 acc[2][2];                          // [o-tile 32][w-half]
    #pragma unroll
    for (int ot = 0; ot < 2; ++ot)
        #pragma unroll
        for (int t = 0; t < 2; ++t)
            #pragma unroll
            for (int e = 0; e < 16; ++e) acc[ot][t][e] = 0.f;

    // per-lane bases
    const char* ldsb = (const char*)lds + (hrow * 4224 + lh * 1056 + l31 * 16);
    // new wb layout: lane-invariant base; a-frag = 2x512B contiguous segments
    const unsigned short* wA = wb + lh * 2048 + (owave + l31) * 8;   // elements

    load_chunk(0);
    write_chunk(0);
    __syncthreads();

    for (int c = 0; c < 8; ++c) {
        const char* bufb = ldsb + (c & 1) * 16896;
        const unsigned short* wc = wA + c * 8192;

        // taps (dy,dx): k0=(1,1) k1=(0,1) k2=(1,0) k3=(1,2) k4=(2,1)
        #pragma unroll
        for (int ks = 0; ks < 2; ++ks) {
            #pragma unroll
            for (int k = 0; k < KT; ++k) {
                const int dy = (k == 1) ? 0 : (k == 4) ? 2 : 1;
                const int dx = (k == 2) ? 0 : (k == 3) ? 2 : 1;
                const short8 a0 = *(const short8*)(wc + k * 65536 + ks * 4096);
                const short8 a1 = *(const short8*)(wc + k * 65536 + ks * 4096 + 256);
                const short8 b0 = *(const short8*)(bufb + (dy * 264 + ks * 132 + dx) * 16);
                const short8 b1 = *(const short8*)(bufb + (dy * 264 + ks * 132 + 32 + dx) * 16);
                acc[0][0] = __builtin_amdgcn_mfma_f32_32x32x16_bf16(a0, b0, acc[0][0], 0, 0, 0);
                acc[1][0] = __builtin_amdgcn_mfma_f32_32x32x16_bf16(a1, b0, acc[1][0], 0, 0, 0);
                acc[0][1] = __builtin_amdgcn_mfma_f32_32x32x16_bf16(a0, b1, acc[0][1], 0, 0, 0);
                acc[1][1] = __builtin_amdgcn_mfma_f32_32x32x16_bf16(a1, b1, acc[1][1], 0, 0, 0);
            }
            // x-prefetch issued mid-chunk: ks=0's a-frag waits (vmcnt FIFO)
            // are not gated on these HBM loads; ks=1 gives them cover.
            if (ks == 0 && c < 7) load_chunk(c + 1);
        }

        if (c < 7) write_chunk((c + 1) & 1);    // other buffer; safe after prev barrier
        __syncthreads();
    }

    // epilogue: C/D: col(px) = l31, row(o-off) = (reg&3) + 8*(reg>>2) + 4*lh
    const int h = h0 + hrow;
    #pragma unroll
    for (int ot = 0; ot < 2; ++ot) {
        #pragma unroll
        for (int wh = 0; wh < 2; ++wh) {
            #pragma unroll
            for (int reg = 0; reg < 16; ++reg) {
                int o = owave + ot * 32 + (reg & 3) + 8 * (reg >> 2) + 4 * lh;
                out[(((size_t)n * CO + o) * 64 + h) * 64 + wh * 32 + l31] = acc[ot][wh][reg];
            }
        }
    }
}

extern "C" void kernel_launch(void* const* d_in, const int* in_sizes, int n_in,
                              void* d_out, int out_size, void* d_ws, size_t ws_size,
                              hipStream_t stream) {
    const float* x = (const float*)d_in[0];
    const float* w = (const float*)d_in[1];
    float* out = (float*)d_out;

    unsigned short* wb = (unsigned short*)d_ws;    // 640 KB, the only workspace

    wtrans_kernel<<<dim3((KT * CO * CI + 255) / 256), dim3(256), 0, stream>>>(w, wb);
    conv_mfma<<<dim3(N_ * 32), dim3(512), 0, stream>>>(x, wb, out);
}

// Round 6
// 148.713 us; speedup vs baseline: 1.2541x; 1.0189x over previous
//
#include <hip/hip_runtime.h>
#include <hip/hip_bf16.h>
#include <cstddef>

// SpatialConv KERNEL_TYPE=0: 5-tap plus conv, N=16 Ci=Co=256 H=W=64, fp32 I/O.
// v4b: 16-phase pipeline, compute phases are LDS-only (T3+T4 from the 8-phase
// GEMM template). Weights staged to LDS via global_load_lds (double-buffered
// 40KB per ks-half); x reg-staged fp32->bf16 double-buffered. Raw s_barrier
// with counted s_waitcnt vmcnt(16) -- x prefetch loads stay in flight across
// the phase barrier. v4b fix: phase-A trailing wait drains lgkmcnt too (DMA
// into wbuf0 next phase vs in-flight ds_reads), sched_barrier(0) on both
// sides of each barrier (rule #18). 1 block/CU (113KB LDS), 8 waves.
#define N_  16
#define CI  256
#define CO  256
#define KT  5

#define XBUF_B   16896        // one x buffer: 1056 cells * 16B
#define WOFF     33792        // 2 x buffers
#define WBUF_B   40960        // one weight buffer: 40KB (5 taps x 8KB)
#define SMEM_B   115712       // 33792 + 2*40960

typedef __attribute__((ext_vector_type(8)))  short  short8;
typedef __attribute__((ext_vector_type(8)))  unsigned short ushort8;
typedef __attribute__((ext_vector_type(4)))  unsigned int uint4v;
typedef __attribute__((ext_vector_type(16))) float  floatx16;

static __device__ __forceinline__ unsigned short f2bf(float f) {
    union { float f; unsigned u; } v; v.f = f;
    unsigned r = v.u + 0x7fff + ((v.u >> 16) & 1);   // RNE
    return (unsigned short)(r >> 16);
}

typedef const __attribute__((address_space(1))) unsigned int g_u32;
typedef __attribute__((address_space(3))) unsigned int l_u32;
static __device__ __forceinline__ void gload_lds16(const void* g, void* l) {
    __builtin_amdgcn_global_load_lds((g_u32*)g, (l_u32*)l, 16, 0, 0);
}

// ---- prepass: w fp32 [Co][Ci][5] -> wb bf16, layout (elements):
//   idx = ((((k*8 + c)*2 + ks)*2 + lh)*256 + o)*8 + e,  ci = c*32+ks*16+lh*8+e
// byte strides: e 2, o 16, lh 4096, ks 8192, c 16384, k 131072.
__global__ void wtrans_kernel(const float* __restrict__ w, unsigned short* __restrict__ wb) {
    int idx = blockIdx.x * 256 + threadIdx.x;
    if (idx >= KT * CO * CI) return;
    int e  = idx & 7;
    int o  = (idx >> 3) & 255;
    int lh = (idx >> 11) & 1;
    int ks = (idx >> 12) & 1;
    int c  = (idx >> 13) & 7;
    int k  = idx >> 16;
    int ci = c * 32 + ks * 16 + lh * 8 + e;
    wb[idx] = f2bf(w[(size_t)o * (CI * KT) + ci * KT + k]);
}

template<int KS>
static __device__ __forceinline__ void compute_half(const char* wB, const char* xB,
                                                    floatx16 (&acc)[2][2]) {
    #pragma unroll
    for (int k = 0; k < KT; ++k) {
        // taps (dy,dx): k0=(1,1) k1=(0,1) k2=(1,0) k3=(1,2) k4=(2,1)
        const int dy = (k == 1) ? 0 : (k == 4) ? 2 : 1;
        const int dx = (k == 2) ? 0 : (k == 3) ? 2 : 1;
        const short8 a0 = *(const short8*)(wB + k * 8192);
        const short8 a1 = *(const short8*)(wB + k * 8192 + 512);
        const short8 b0 = *(const short8*)(xB + (dy * 264 + KS * 132 + dx) * 16);
        const short8 b1 = *(const short8*)(xB + (dy * 264 + KS * 132 + 32 + dx) * 16);
        acc[0][0] = __builtin_amdgcn_mfma_f32_32x32x16_bf16(a0, b0, acc[0][0], 0, 0, 0);
        acc[1][0] = __builtin_amdgcn_mfma_f32_32x32x16_bf16(a1, b0, acc[1][0], 0, 0, 0);
        acc[0][1] = __builtin_amdgcn_mfma_f32_32x32x16_bf16(a0, b1, acc[0][1], 0, 0, 0);
        acc[1][1] = __builtin_amdgcn_mfma_f32_32x32x16_bf16(a1, b1, acc[1][1], 0, 0, 0);
    }
}

// ---- main: block = 256 o x 2 rows x 64 w, 8 waves; wave = 64 o x 1 row ----
// x LDS: cell = buf*1056 + r*264 + cg*66 + wp (16B cells), wp=w+1, pads zeroed.
// w LDS: WOFF + buf*40960 + k*8192 + lh*4096 + o*16 (linear mirror of wb chunk).
__global__ __launch_bounds__(512, 2) void conv_mfma(const float* __restrict__ x,
                                                    const unsigned short* __restrict__ wb,
                                                    float* __restrict__ out) {
    extern __shared__ char smem[];

    const int tid = threadIdx.x;
    const int bx0 = blockIdx.x;
    const int bx  = (bx0 & 7) * 64 + (bx0 >> 3);   // XCD-bijective (512 = 8*64)
    const int g   = bx & 31;                        // row-pair: rows 2g, 2g+1
    const int n   = bx >> 5;
    const int h0  = g * 2;

    const int lane  = tid & 63;
    const int wv    = tid >> 6;                 // 0..7
    const int l31   = lane & 31;
    const int lh    = lane >> 5;
    const int owave = (wv & 3) * 64;
    const int hrow  = wv >> 2;

    const int sw  = tid & 63;
    const int scg = (tid >> 6) & 3;
    const int sr2 = tid >> 8;                   // 0/1

    // zero horizontal pad cells (both x buffers)
    if (tid < 64) {
        int buf = tid & 1;
        int wp  = ((tid >> 1) & 1) * 65;
        int cg  = (tid >> 2) & 3;
        int r   = (tid >> 4) & 3;
        ((ushort8*)smem)[buf * 1056 + r * 264 + cg * 66 + wp] = (ushort8)0;
    }

    const float* xn = x + (size_t)n * CI * 4096;

    // branchless edge handling: always 16 loads/thread (exact per-wave vmcnt
    // count!), clamped row addr; zero-mask applied at the bf16 pack.
    float zm[2];
    int   hcl[2];
    #pragma unroll
    for (int ii = 0; ii < 2; ++ii) {
        int hh = h0 - 1 + sr2 * 2 + ii;
        zm[ii]  = ((unsigned)hh < 64u) ? 1.f : 0.f;
        hcl[ii] = hh < 0 ? 0 : (hh > 63 ? 63 : hh);
    }

    float xr[2][8];
    auto load_chunk = [&](int c) {
        #pragma unroll
        for (int ii = 0; ii < 2; ++ii) {
            const float* p = xn + (c * 32 + scg * 8) * 4096 + hcl[ii] * 64 + sw;
            #pragma unroll
            for (int e = 0; e < 8; ++e) xr[ii][e] = p[e * 4096];
        }
    };
    auto write_chunk = [&](int b) {
        #pragma unroll
        for (int ii = 0; ii < 2; ++ii) {
            const int i = sr2 * 2 + ii;
            uint4v v;
            #pragma unroll
            for (int e = 0; e < 4; ++e) {
                __hip_bfloat162 pk = __float22bfloat162_rn(
                    make_float2(zm[ii] * xr[ii][2 * e], zm[ii] * xr[ii][2 * e + 1]));
                union { __hip_bfloat162 h; unsigned u; } cv; cv.h = pk;
                v[e] = cv.u;
            }
            *(uint4v*)&((ushort8*)smem)[b * 1056 + i * 264 + scg * 66 + (sw + 1)] = v;
        }
    };
    // stage weights for (c, ks) into wbuf[buf]: 5 x 1KB global_load_lds per wave
    auto stage_w = [&](int c, int ks, int buf) {
        const char* src = (const char*)wb + c * 16384 + ks * 8192 + wv * 1024 + lane * 16;
        char* dst = smem + WOFF + buf * WBUF_B + wv * 1024;
        #pragma unroll
        for (int i = 0; i < 5; ++i)
            gload_lds16(src + (size_t)i * 131072, dst + i * 8192);
    };

    floatx16 acc[2][2];
    #pragma unroll
    for (int ot = 0; ot < 2; ++ot)
        #pragma unroll
        for (int t = 0; t < 2; ++t)
            #pragma unroll
            for (int e = 0; e < 16; ++e) acc[ot][t][e] = 0.f;

    const char* xbase = smem + hrow * 4224 + lh * 1056 + l31 * 16;
    const char* wbase = smem + WOFF + lh * 4096 + (owave + l31) * 16;

    // ---- prologue: weights (0,0) -> wbuf0, x chunk 0 -> xbuf0 ----
    stage_w(0, 0, 0);
    load_chunk(0);
    write_chunk(0);                                   // compiler waits vmcnt for xr
    __builtin_amdgcn_sched_barrier(0);
    asm volatile("s_waitcnt vmcnt(0) lgkmcnt(0)" ::: "memory");
    __builtin_amdgcn_s_barrier();
    __builtin_amdgcn_sched_barrier(0);

    for (int c = 0; c < 8; ++c) {
        const char* xb = xbase + (c & 1) * XBUF_B;

        // ---- phase A (ks=0): reads wbuf0 + xbuf[c&1] ----
        stage_w(c, 1, 1);                             // 5 loads (oldest in FIFO)
        asm volatile("" ::: "memory");
        if (c < 7) load_chunk(c + 1);                 // 16 loads (younger)
        asm volatile("" ::: "memory");
        compute_half<0>(wbase, xb, acc);              // pure LDS + MFMA
        __builtin_amdgcn_sched_barrier(0);
        // w landed (oldest 5), x stays in flight across barrier; lgkm drain
        // guards wbuf0 ds_reads vs next phase's DMA overwrite (rule #18).
        if (c < 7) asm volatile("s_waitcnt vmcnt(16) lgkmcnt(0)" ::: "memory");
        else       asm volatile("s_waitcnt vmcnt(0) lgkmcnt(0)"  ::: "memory");
        __builtin_amdgcn_s_barrier();
        __builtin_amdgcn_sched_barrier(0);

        // ---- phase B (ks=1): reads wbuf1 + xbuf[c&1] ----
        if (c < 7) stage_w(c + 1, 0, 0);              // 5 loads
        asm volatile("" ::: "memory");
        if (c < 7) write_chunk((c + 1) & 1);          // auto vmcnt(5) for xr, then ds_write
        asm volatile("" ::: "memory");
        compute_half<1>(wbase + WBUF_B, xb, acc);
        __builtin_amdgcn_sched_barrier(0);
        if (c < 7) {
            asm volatile("s_waitcnt vmcnt(0) lgkmcnt(0)" ::: "memory");
            __builtin_amdgcn_s_barrier();
            __builtin_amdgcn_sched_barrier(0);
        }
    }

    // epilogue: C/D: col(px) = l31, row(o-off) = (reg&3) + 8*(reg>>2) + 4*lh
    const int h = h0 + hrow;
    #pragma unroll
    for (int ot = 0; ot < 2; ++ot) {
        #pragma unroll
        for (int wh = 0; wh < 2; ++wh) {
            #pragma unroll
            for (int reg = 0; reg < 16; ++reg) {
                int o = owave + ot * 32 + (reg & 3) + 8 * (reg >> 2) + 4 * lh;
                out[(((size_t)n * CO + o) * 64 + h) * 64 + wh * 32 + l31] = acc[ot][wh][reg];
            }
        }
    }
}

extern "C" void kernel_launch(void* const* d_in, const int* in_sizes, int n_in,
                              void* d_out, int out_size, void* d_ws, size_t ws_size,
                              hipStream_t stream) {
    const float* x = (const float*)d_in[0];
    const float* w = (const float*)d_in[1];
    float* out = (float*)d_out;

    unsigned short* wb = (unsigned short*)d_ws;    // 640 KB, the only workspace

    static bool attr_set = false;
    if (!attr_set) {
        hipFuncSetAttribute(reinterpret_cast<const void*>(conv_mfma),
                            hipFuncAttributeMaxDynamicSharedMemorySize, SMEM_B);
        attr_set = true;
    }

    wtrans_kernel<<<dim3((KT * CO * CI + 255) / 256), dim3(256), 0, stream>>>(w, wb);
    conv_mfma<<<dim3(N_ * 32), dim3(512), SMEM_B, stream>>>(x, wb, out);
}